// Round 1
// baseline (2984.089 us; speedup 1.0000x reference)
//
#include <hip/hip_runtime.h>

#define BATCH 512
#define TT 256
#define HH 256
#define HOR 22

__device__ __forceinline__ float bf16lo(unsigned u) { return __uint_as_float(u << 16); }
__device__ __forceinline__ float bf16hi(unsigned u) { return __uint_as_float(u & 0xFFFF0000u); }
__device__ __forceinline__ float rcp_(float x) { return __builtin_amdgcn_rcpf(x); }
__device__ __forceinline__ float sigmoidf_(float x) { return rcp_(1.0f + __expf(-x)); }
__device__ __forceinline__ float tanhf_(float x) {
    float e = __expf(-2.0f * fabsf(x));
    float t = (1.0f - e) * rcp_(1.0f + e);
    return copysignf(t, x);
}

// ---------------- prep: transpose U matrices to bf16 rows (UT[j][k]) ----------------
__device__ __forceinline__ unsigned f2bf_rne(float f) {
    unsigned u = __float_as_uint(f);
    unsigned lsb = (u >> 16) & 1u;
    return (u + 0x7FFFu + lsb) >> 16;
}

__global__ __launch_bounds__(256) void prep_kernel(const float* __restrict__ Uz,
                                                   const float* __restrict__ Ur,
                                                   const float* __restrict__ Uh,
                                                   unsigned* __restrict__ UzT,
                                                   unsigned* __restrict__ UrT,
                                                   unsigned* __restrict__ UhT) {
    int tid = blockIdx.x * 256 + threadIdx.x;   // 0 .. 98303
    int m  = tid >> 15;                          // matrix id 0..2
    int r  = tid & 32767;
    int j  = r & 255;                            // output column (dest row)
    int kp = r >> 8;                             // k-pair 0..127
    const float* src = (m == 0) ? Uz : (m == 1) ? Ur : Uh;
    unsigned*    dst = (m == 0) ? UzT : (m == 1) ? UrT : UhT;
    float a0 = src[(2 * kp)     * HH + j];
    float a1 = src[(2 * kp + 1) * HH + j];
    dst[j * (HH / 2) + kp] = f2bf_rne(a0) | (f2bf_rne(a1) << 16);
}

// ---------------- main persistent GRU kernel: 1 WG = 2 batch rows ----------------
// acc update for one packed uint (2 bf16 weights) against two float2 h pairs
#define ACC2(U32, H4, A0, A1)                         \
    {                                                 \
        float wlo = bf16lo(U32), whi = bf16hi(U32);   \
        A0 += (H4).x * wlo;  A1 += (H4).y * wlo;      \
        A0 += (H4).z * whi;  A1 += (H4).w * whi;      \
    }

__global__ __launch_bounds__(256) void gru_kernel(
    const float* __restrict__ x,
    const float* __restrict__ Wzw, const float* __restrict__ Wzb, const float* __restrict__ Uzb,
    const float* __restrict__ Wrw, const float* __restrict__ Wrb, const float* __restrict__ Urb,
    const float* __restrict__ Whw, const float* __restrict__ Whb, const float* __restrict__ Uhb,
    const float* __restrict__ Wgw, const float* __restrict__ Wgb,
    const float* __restrict__ om_raw, const float* __restrict__ al_raw,
    const float* __restrict__ be_raw, const float* __restrict__ gam,
    const float* __restrict__ fc1w, const float* __restrict__ fc1b,
    const float* __restrict__ fc2w, const float* __restrict__ fc2b,
    const unsigned* __restrict__ UzT, const unsigned* __restrict__ UrT,
    const unsigned* __restrict__ UhT,
    float* __restrict__ out) {
    __shared__ __align__(16) float2 h01[HH];   // (h for b0, h for b1)
    __shared__ __align__(16) float2 rh01[HH];  // r*h pairs / later hid

    const int j  = threadIdx.x;
    const int b0 = blockIdx.x * 2;
    const int b1 = b0 + 1;

    // scalar params (uniform)
    const float omega = log1pf(__expf(om_raw[0])) + 1e-6f;
    const float aco   = sigmoidf_(al_raw[0]);
    const float bco   = sigmoidf_(be_raw[0]) * (1.0f - aco * 0.99f);
    const float gma   = gam[0];

    // per-column params
    const float wz = Wzw[j], bz = Wzb[j] + Uzb[j];
    const float wr = Wrw[j], br = Wrb[j] + Urb[j];
    const float wh = Whw[j], bh = Whb[j] + Uhb[j];
    const float wg = Wgw[j], bg = Wgb[j];

    const uint4* uz = (const uint4*)(UzT + j * (HH / 2));  // 32 uint4 per row
    const uint4* ur = (const uint4*)(UrT + j * (HH / 2));
    const uint4* uh = (const uint4*)(UhT + j * (HH / 2));

    h01[j] = make_float2(0.f, 0.f);
    float hown0 = 0.f, hown1 = 0.f;
    float eps0 = 1e-6f, sig0 = 1e-6f;
    float eps1 = 1e-6f, sig1 = 1e-6f;
    __syncthreads();

    const float4* hv  = (const float4*)h01;   // 128 float4 = pairs of float2
    const float4* rhv = (const float4*)rh01;

    for (int t = 0; t < TT; ++t) {
        const float x0 = x[b0 * TT + t];
        const float x1 = x[b1 * TT + t];
        const float g0 = omega + aco * eps0 + bco * sig0;
        const float g1 = omega + aco * eps1 + bco * sig1;
        eps0 = x0 * x0; sig0 = g0;
        eps1 = x1 * x1; sig1 = g1;

        // ---- phase A: z and r gates ----
        float az0 = 0.f, az1 = 0.f, ar0 = 0.f, ar1 = 0.f;
        float az0b = 0.f, az1b = 0.f, ar0b = 0.f, ar1b = 0.f;
#pragma unroll 4
        for (int c = 0; c < 32; ++c) {
            uint4 wzc = uz[c];
            uint4 wrc = ur[c];
            float4 hA = hv[4 * c + 0];
            float4 hB = hv[4 * c + 1];
            float4 hC = hv[4 * c + 2];
            float4 hD = hv[4 * c + 3];
            ACC2(wzc.x, hA, az0, az1);
            ACC2(wzc.y, hB, az0b, az1b);
            ACC2(wzc.z, hC, az0, az1);
            ACC2(wzc.w, hD, az0b, az1b);
            ACC2(wrc.x, hA, ar0, ar1);
            ACC2(wrc.y, hB, ar0b, ar1b);
            ACC2(wrc.z, hC, ar0, ar1);
            ACC2(wrc.w, hD, ar0b, ar1b);
        }
        az0 += az0b; az1 += az1b; ar0 += ar0b; ar1 += ar1b;

        const float z0 = sigmoidf_(x0 * wz + bz + az0);
        const float z1 = sigmoidf_(x1 * wz + bz + az1);
        const float r0 = sigmoidf_(x0 * wr + br + ar0);
        const float r1 = sigmoidf_(x1 * wr + br + ar1);
        rh01[j] = make_float2(r0 * hown0, r1 * hown1);
        __syncthreads();

        // ---- phase B: candidate gate ----
        float ah0 = 0.f, ah1 = 0.f, ah0b = 0.f, ah1b = 0.f;
#pragma unroll 4
        for (int c = 0; c < 32; ++c) {
            uint4 whc = uh[c];
            float4 pA = rhv[4 * c + 0];
            float4 pB = rhv[4 * c + 1];
            float4 pC = rhv[4 * c + 2];
            float4 pD = rhv[4 * c + 3];
            ACC2(whc.x, pA, ah0, ah1);
            ACC2(whc.y, pB, ah0b, ah1b);
            ACC2(whc.z, pC, ah0, ah1);
            ACC2(whc.w, pD, ah0b, ah1b);
        }
        ah0 += ah0b; ah1 += ah1b;

        const float ht0 = tanhf_(x0 * wh + bh + ah0);
        const float ht1 = tanhf_(x1 * wh + bh + ah1);
        const float hh0 = (1.f - z0) * ht0 + z0 * hown0;
        const float hh1 = (1.f - z1) * ht1 + z1 * hown1;
        const float hn0 = tanhf_(hh0 + gma * (g0 * wg + bg));
        const float hn1 = tanhf_(hh1 + gma * (g1 * wg + bg));
        hown0 = hn0; hown1 = hn1;
        h01[j] = make_float2(hn0, hn1);
        __syncthreads();
    }

    // ---- head: hid = relu(h @ fc1 + b1) ----
    float s0 = 0.f, s1 = 0.f;
#pragma unroll 4
    for (int k = 0; k < HH; ++k) {
        float w  = fc1w[k * HH + j];
        float2 hk = h01[k];
        s0 += hk.x * w;
        s1 += hk.y * w;
    }
    const float hid0 = fmaxf(s0 + fc1b[j], 0.f);
    const float hid1 = fmaxf(s1 + fc1b[j], 0.f);
    rh01[j] = make_float2(hid0, hid1);
    __syncthreads();

    // ---- head: nn_scale / vol ----
    if (j < 2 * HOR) {
        const int s = j / HOR;    // batch select
        const int c = j % HOR;    // horizon col
        float acc = fc2b[c];
        for (int k = 0; k < HH; ++k) {
            float2 hk = rh01[k];
            acc += (s ? hk.y : hk.x) * fc2w[k * HOR + c];
        }
        const float sp  = log1pf(__expf(acc));
        const float sg  = s ? sig1 : sig0;
        const float vb  = sqrtf(sg + 1e-8f);
        float vol = vb * (1.0f + sp);
        vol = fminf(fmaxf(vol, 0.01f), 10.0f);
        out[(s ? b1 : b0) * HOR + c] = vol;
    }
    if (j == 0) out[BATCH * HOR + b0] = sig0;
    if (j == 1) out[BATCH * HOR + b1] = sig1;
}

extern "C" void kernel_launch(void* const* d_in, const int* in_sizes, int n_in,
                              void* d_out, int out_size, void* d_ws, size_t ws_size,
                              hipStream_t stream) {
    const float* x    = (const float*)d_in[0];
    const float* Wzw  = (const float*)d_in[1];
    const float* Wzb  = (const float*)d_in[2];
    const float* Uzw  = (const float*)d_in[3];
    const float* Uzb  = (const float*)d_in[4];
    const float* Wrw  = (const float*)d_in[5];
    const float* Wrb  = (const float*)d_in[6];
    const float* Urw  = (const float*)d_in[7];
    const float* Urb  = (const float*)d_in[8];
    const float* Whw  = (const float*)d_in[9];
    const float* Whb  = (const float*)d_in[10];
    const float* Uhw  = (const float*)d_in[11];
    const float* Uhb  = (const float*)d_in[12];
    const float* Wgw  = (const float*)d_in[13];
    const float* Wgb  = (const float*)d_in[14];
    const float* om   = (const float*)d_in[15];
    const float* al   = (const float*)d_in[16];
    const float* be   = (const float*)d_in[17];
    const float* ga   = (const float*)d_in[18];
    const float* fc1w = (const float*)d_in[19];
    const float* fc1b = (const float*)d_in[20];
    const float* fc2w = (const float*)d_in[21];
    const float* fc2b = (const float*)d_in[22];

    unsigned* UzT = (unsigned*)d_ws;       // 32768 uints each
    unsigned* UrT = UzT + 32768;
    unsigned* UhT = UrT + 32768;

    prep_kernel<<<384, 256, 0, stream>>>(Uzw, Urw, Uhw, UzT, UrT, UhT);
    gru_kernel<<<256, 256, 0, stream>>>(x, Wzw, Wzb, Uzb, Wrw, Wrb, Urb, Whw, Whb, Uhb,
                                        Wgw, Wgb, om, al, be, ga, fc1w, fc1b, fc2w, fc2b,
                                        UzT, UrT, UhT, (float*)d_out);
}

// Round 2
// 1580.337 us; speedup vs baseline: 1.8883x; 1.8883x over previous
//
#include <hip/hip_runtime.h>

#define BATCH 512
#define TT 256
#define HH 256
#define HOR 22

__device__ __forceinline__ float bf16lo(unsigned u) { return __uint_as_float(u << 16); }
__device__ __forceinline__ float bf16hi(unsigned u) { return __uint_as_float(u & 0xFFFF0000u); }
__device__ __forceinline__ float rcp_(float x) { return __builtin_amdgcn_rcpf(x); }
__device__ __forceinline__ float sigmoidf_(float x) { return rcp_(1.0f + __expf(-x)); }
__device__ __forceinline__ float tanhf_(float x) {
    float e = __expf(-2.0f * fabsf(x));
    float t = (1.0f - e) * rcp_(1.0f + e);
    return copysignf(t, x);
}
__device__ __forceinline__ unsigned f2bf_rne(float f) {
    unsigned u = __float_as_uint(f);
    unsigned lsb = (u >> 16) & 1u;
    return (u + 0x7FFFu + lsb) >> 16;
}

// v_dot2_f32_bf16: acc += a.lo*b.lo + a.hi*b.hi (packed bf16 pairs in 32-bit regs)
#define DOT2(acc, a, b) asm("v_dot2_f32_bf16 %0, %1, %2, %0" : "+v"(acc) : "v"(a), "v"(b))

// ---------------- prep: transpose U matrices to packed-bf16 rows UT[j][kpair] ----------------
__global__ __launch_bounds__(256) void prep_kernel(const float* __restrict__ Uz,
                                                   const float* __restrict__ Ur,
                                                   const float* __restrict__ Uh,
                                                   unsigned* __restrict__ UzT,
                                                   unsigned* __restrict__ UrT,
                                                   unsigned* __restrict__ UhT) {
    int tid = blockIdx.x * 256 + threadIdx.x;   // 0 .. 98303
    int m  = tid >> 15;                          // matrix id 0..2
    int r  = tid & 32767;
    int j  = r & 255;                            // output column (dest row)
    int kp = r >> 8;                             // k-pair 0..127
    const float* src = (m == 0) ? Uz : (m == 1) ? Ur : Uh;
    unsigned*    dst = (m == 0) ? UzT : (m == 1) ? UrT : UhT;
    float a0 = src[(2 * kp)     * HH + j];
    float a1 = src[(2 * kp + 1) * HH + j];
    dst[j * (HH / 2) + kp] = f2bf_rne(a0) | (f2bf_rne(a1) << 16);
}

// ---------------- persistent GRU: 1 WG = 2 batch rows, U in registers ----------------
__global__ __launch_bounds__(256) void gru_kernel(
    const float* __restrict__ x,
    const float* __restrict__ Wzw, const float* __restrict__ Wzb, const float* __restrict__ Uzb,
    const float* __restrict__ Wrw, const float* __restrict__ Wrb, const float* __restrict__ Urb,
    const float* __restrict__ Whw, const float* __restrict__ Whb, const float* __restrict__ Uhb,
    const float* __restrict__ Wgw, const float* __restrict__ Wgb,
    const float* __restrict__ om_raw, const float* __restrict__ al_raw,
    const float* __restrict__ be_raw, const float* __restrict__ gam,
    const float* __restrict__ fc1w, const float* __restrict__ fc1b,
    const float* __restrict__ fc2w, const float* __restrict__ fc2b,
    const unsigned* __restrict__ UzT, const unsigned* __restrict__ UrT,
    const unsigned* __restrict__ UhT,
    float* __restrict__ out) {
    __shared__ __align__(16) unsigned hpk[2][128];   // h as packed bf16 pairs, per batch
    __shared__ __align__(16) unsigned rhpk[2][128];  // r*h packed bf16 pairs
    __shared__ float xr[2][TT];                      // staged x rows (fp32, exact)
    __shared__ float hidf[2][HH];                    // head hidden (fp32)

    const int j  = threadIdx.x;
    const int b0 = blockIdx.x * 2;
    const int b1 = b0 + 1;

    // ---- load this thread's 3 weight rows into registers (384 VGPRs) ----
    uint4 wzr[32], wrr[32], whr[32];
    {
        const uint4* uz = (const uint4*)(UzT + j * (HH / 2));
        const uint4* ur = (const uint4*)(UrT + j * (HH / 2));
        const uint4* uh = (const uint4*)(UhT + j * (HH / 2));
#pragma unroll
        for (int c = 0; c < 32; ++c) wzr[c] = uz[c];
#pragma unroll
        for (int c = 0; c < 32; ++c) wrr[c] = ur[c];
#pragma unroll
        for (int c = 0; c < 32; ++c) whr[c] = uh[c];
    }

    // scalar params (uniform)
    const float omega = log1pf(__expf(om_raw[0])) + 1e-6f;
    const float aco   = sigmoidf_(al_raw[0]);
    const float bco   = sigmoidf_(be_raw[0]) * (1.0f - aco * 0.99f);
    const float gma   = gam[0];

    // per-column params
    const float wz = Wzw[j], bz = Wzb[j] + Uzb[j];
    const float wr = Wrw[j], br = Wrb[j] + Urb[j];
    const float wh = Whw[j], bh = Whb[j] + Uhb[j];
    const float wg = Wgw[j], bg = Wgb[j];

    // stage x rows; init h
    xr[0][j] = x[b0 * TT + j];
    xr[1][j] = x[b1 * TT + j];
    ((unsigned short*)hpk)[j]       = 0;   // h[b0][j] = 0 (bf16)
    ((unsigned short*)hpk)[256 + j] = 0;   // h[b1][j] = 0
    float hown0 = 0.f, hown1 = 0.f;
    float eps0 = 1e-6f, sig0 = 1e-6f;
    float eps1 = 1e-6f, sig1 = 1e-6f;
    __syncthreads();

    const uint4* hv0  = (const uint4*)hpk[0];
    const uint4* hv1  = (const uint4*)hpk[1];
    const uint4* rhv0 = (const uint4*)rhpk[0];
    const uint4* rhv1 = (const uint4*)rhpk[1];
    unsigned short* hp  = (unsigned short*)hpk;
    unsigned short* rhp = (unsigned short*)rhpk;

    for (int t = 0; t < TT; ++t) {
        const float x0 = xr[0][t];
        const float x1 = xr[1][t];
        const float g0 = omega + aco * eps0 + bco * sig0;
        const float g1 = omega + aco * eps1 + bco * sig1;
        eps0 = x0 * x0; sig0 = g0;
        eps1 = x1 * x1; sig1 = g1;

        // ---- phase A: z and r gate dot products (all from registers + LDS broadcast) ----
        float az0a = 0.f, az0b = 0.f, az1a = 0.f, az1b = 0.f;
        float ar0a = 0.f, ar0b = 0.f, ar1a = 0.f, ar1b = 0.f;
#pragma unroll
        for (int c = 0; c < 32; ++c) {
            uint4 h0 = hv0[c];
            uint4 h1 = hv1[c];
            uint4 wzc = wzr[c];
            uint4 wrc = wrr[c];
            DOT2(az0a, wzc.x, h0.x); DOT2(az0b, wzc.y, h0.y);
            DOT2(az0a, wzc.z, h0.z); DOT2(az0b, wzc.w, h0.w);
            DOT2(az1a, wzc.x, h1.x); DOT2(az1b, wzc.y, h1.y);
            DOT2(az1a, wzc.z, h1.z); DOT2(az1b, wzc.w, h1.w);
            DOT2(ar0a, wrc.x, h0.x); DOT2(ar0b, wrc.y, h0.y);
            DOT2(ar0a, wrc.z, h0.z); DOT2(ar0b, wrc.w, h0.w);
            DOT2(ar1a, wrc.x, h1.x); DOT2(ar1b, wrc.y, h1.y);
            DOT2(ar1a, wrc.z, h1.z); DOT2(ar1b, wrc.w, h1.w);
        }
        const float z0 = sigmoidf_(x0 * wz + bz + az0a + az0b);
        const float z1 = sigmoidf_(x1 * wz + bz + az1a + az1b);
        const float r0 = sigmoidf_(x0 * wr + br + ar0a + ar0b);
        const float r1 = sigmoidf_(x1 * wr + br + ar1a + ar1b);
        rhp[j]       = (unsigned short)f2bf_rne(r0 * hown0);
        rhp[256 + j] = (unsigned short)f2bf_rne(r1 * hown1);
        __syncthreads();

        // ---- phase B: candidate gate ----
        float ah0a = 0.f, ah0b = 0.f, ah1a = 0.f, ah1b = 0.f;
#pragma unroll
        for (int c = 0; c < 32; ++c) {
            uint4 p0 = rhv0[c];
            uint4 p1 = rhv1[c];
            uint4 whc = whr[c];
            DOT2(ah0a, whc.x, p0.x); DOT2(ah0b, whc.y, p0.y);
            DOT2(ah0a, whc.z, p0.z); DOT2(ah0b, whc.w, p0.w);
            DOT2(ah1a, whc.x, p1.x); DOT2(ah1b, whc.y, p1.y);
            DOT2(ah1a, whc.z, p1.z); DOT2(ah1b, whc.w, p1.w);
        }
        const float ht0 = tanhf_(x0 * wh + bh + ah0a + ah0b);
        const float ht1 = tanhf_(x1 * wh + bh + ah1a + ah1b);
        const float hh0 = (1.f - z0) * ht0 + z0 * hown0;
        const float hh1 = (1.f - z1) * ht1 + z1 * hown1;
        const float hn0 = tanhf_(hh0 + gma * (g0 * wg + bg));
        const float hn1 = tanhf_(hh1 + gma * (g1 * wg + bg));
        hown0 = hn0; hown1 = hn1;
        hp[j]       = (unsigned short)f2bf_rne(hn0);
        hp[256 + j] = (unsigned short)f2bf_rne(hn1);
        __syncthreads();
    }

    // ---- head: hid = relu(h @ fc1 + b1) ----
    float s0 = 0.f, s1 = 0.f;
#pragma unroll 4
    for (int kp = 0; kp < 128; ++kp) {
        unsigned p0 = hpk[0][kp];
        unsigned p1 = hpk[1][kp];
        float w0 = fc1w[(2 * kp) * HH + j];
        float w1 = fc1w[(2 * kp + 1) * HH + j];
        s0 += bf16lo(p0) * w0 + bf16hi(p0) * w1;
        s1 += bf16lo(p1) * w0 + bf16hi(p1) * w1;
    }
    hidf[0][j] = fmaxf(s0 + fc1b[j], 0.f);
    hidf[1][j] = fmaxf(s1 + fc1b[j], 0.f);
    __syncthreads();

    // ---- head: nn_scale / vol ----
    if (j < 2 * HOR) {
        const int s = j / HOR;    // batch select
        const int c = j % HOR;    // horizon col
        float acc = fc2b[c];
        for (int k = 0; k < HH; ++k) {
            acc += hidf[s][k] * fc2w[k * HOR + c];
        }
        const float sp = log1pf(__expf(acc));
        const float sg = s ? sig1 : sig0;
        const float vb = sqrtf(sg + 1e-8f);
        float vol = vb * (1.0f + sp);
        vol = fminf(fmaxf(vol, 0.01f), 10.0f);
        out[(s ? b1 : b0) * HOR + c] = vol;
    }
    if (j == 0) out[BATCH * HOR + b0] = sig0;
    if (j == 1) out[BATCH * HOR + b1] = sig1;
}

extern "C" void kernel_launch(void* const* d_in, const int* in_sizes, int n_in,
                              void* d_out, int out_size, void* d_ws, size_t ws_size,
                              hipStream_t stream) {
    const float* x    = (const float*)d_in[0];
    const float* Wzw  = (const float*)d_in[1];
    const float* Wzb  = (const float*)d_in[2];
    const float* Uzw  = (const float*)d_in[3];
    const float* Uzb  = (const float*)d_in[4];
    const float* Wrw  = (const float*)d_in[5];
    const float* Wrb  = (const float*)d_in[6];
    const float* Urw  = (const float*)d_in[7];
    const float* Urb  = (const float*)d_in[8];
    const float* Whw  = (const float*)d_in[9];
    const float* Whb  = (const float*)d_in[10];
    const float* Uhw  = (const float*)d_in[11];
    const float* Uhb  = (const float*)d_in[12];
    const float* Wgw  = (const float*)d_in[13];
    const float* Wgb  = (const float*)d_in[14];
    const float* om   = (const float*)d_in[15];
    const float* al   = (const float*)d_in[16];
    const float* be   = (const float*)d_in[17];
    const float* ga   = (const float*)d_in[18];
    const float* fc1w = (const float*)d_in[19];
    const float* fc1b = (const float*)d_in[20];
    const float* fc2w = (const float*)d_in[21];
    const float* fc2b = (const float*)d_in[22];

    unsigned* UzT = (unsigned*)d_ws;       // 32768 uints each
    unsigned* UrT = UzT + 32768;
    unsigned* UhT = UrT + 32768;

    prep_kernel<<<384, 256, 0, stream>>>(Uzw, Urw, Uhw, UzT, UrT, UhT);
    gru_kernel<<<256, 256, 0, stream>>>(x, Wzw, Wzb, Uzb, Wrw, Wrb, Urb, Whw, Whb, Uhb,
                                        Wgw, Wgb, om, al, be, ga, fc1w, fc1b, fc2w, fc2b,
                                        UzT, UrT, UhT, (float*)d_out);
}

// Round 3
// 797.414 us; speedup vs baseline: 3.7422x; 1.9818x over previous
//
#include <hip/hip_runtime.h>

#define BATCH 512
#define TT 256
#define HH 256
#define HOR 22

__device__ __forceinline__ float bf16lo(unsigned u) { return __uint_as_float(u << 16); }
__device__ __forceinline__ float bf16hi(unsigned u) { return __uint_as_float(u & 0xFFFF0000u); }
__device__ __forceinline__ float rcp_(float x) { return __builtin_amdgcn_rcpf(x); }
__device__ __forceinline__ float sigmoidf_(float x) { return rcp_(1.0f + __expf(-x)); }
__device__ __forceinline__ float tanhf_(float x) {
    float e = __expf(-2.0f * fabsf(x));
    float t = (1.0f - e) * rcp_(1.0f + e);
    return copysignf(t, x);
}
__device__ __forceinline__ unsigned f2bf_rne(float f) {
    unsigned u = __float_as_uint(f);
    unsigned lsb = (u >> 16) & 1u;
    return (u + 0x7FFFu + lsb) >> 16;
}

// v_dot2_f32_bf16: acc += a.lo*b.lo + a.hi*b.hi (packed bf16 pairs)
#define DOT2(acc, a, b) asm("v_dot2_f32_bf16 %0, %1, %2, %0" : "+v"(acc) : "v"(a), "v"(b))

// DPP cross-lane (VALU pipe, no LDS)
#define DPPF(x, ctrl) __int_as_float(__builtin_amdgcn_update_dpp(0, __float_as_int(x), (ctrl), 0xF, 0xF, true))
// one reduce-scatter round: combine a (kept if !p) / b (kept if p) with xor-partner via ctrl
#define RCOMB(out, a, b, p, ctrl)                          \
    {                                                      \
        float _ta = (a) + DPPF((a), ctrl);                 \
        float _tb = (b) + DPPF((b), ctrl);                 \
        (out) = (p) ? _tb : _ta;                           \
    }
// xor4 within 16-lane row: lower half reads +4 (row_shl:4=0x104), upper reads -4 (row_shr:4=0x114)
#define RCOMB4(out, a, b, p2v)                                         \
    {                                                                  \
        float _xa = (p2v) ? DPPF((a), 0x114) : DPPF((a), 0x104);       \
        float _xb = (p2v) ? DPPF((b), 0x114) : DPPF((b), 0x104);       \
        float _ta = (a) + _xa;                                         \
        float _tb = (b) + _xb;                                         \
        (out) = (p2v) ? _tb : _ta;                                     \
    }

// ---------------- prep: transpose U matrices to packed-bf16 rows UT[col][kpair] ----------------
__global__ __launch_bounds__(256) void prep_kernel(const float* __restrict__ Uz,
                                                   const float* __restrict__ Ur,
                                                   const float* __restrict__ Uh,
                                                   unsigned* __restrict__ UzT,
                                                   unsigned* __restrict__ UrT,
                                                   unsigned* __restrict__ UhT) {
    int tid = blockIdx.x * 256 + threadIdx.x;   // 0 .. 98303
    int m  = tid >> 15;
    int r  = tid & 32767;
    int j  = r & 255;
    int kp = r >> 8;
    const float* src = (m == 0) ? Uz : (m == 1) ? Ur : Uh;
    unsigned*    dst = (m == 0) ? UzT : (m == 1) ? UrT : UhT;
    float a0 = src[(2 * kp)     * HH + j];
    float a1 = src[(2 * kp + 1) * HH + j];
    dst[j * (HH / 2) + kp] = f2bf_rne(a0) | (f2bf_rne(a1) << 16);
}

// ---------------- persistent GRU: 1 WG = 2 batch rows, 512 thr = 64 col-quads x 8 K-slices ----
__global__ __launch_bounds__(512) void gru_kernel(
    const float* __restrict__ x,
    const float* __restrict__ Wzw, const float* __restrict__ Wzb, const float* __restrict__ Uzb,
    const float* __restrict__ Wrw, const float* __restrict__ Wrb, const float* __restrict__ Urb,
    const float* __restrict__ Whw, const float* __restrict__ Whb, const float* __restrict__ Uhb,
    const float* __restrict__ Wgw, const float* __restrict__ Wgb,
    const float* __restrict__ om_raw, const float* __restrict__ al_raw,
    const float* __restrict__ be_raw, const float* __restrict__ gam,
    const float* __restrict__ fc1w, const float* __restrict__ fc1b,
    const float* __restrict__ fc2w, const float* __restrict__ fc2b,
    const unsigned* __restrict__ UzT, const unsigned* __restrict__ UrT,
    const unsigned* __restrict__ UhT,
    float* __restrict__ out) {
    // h / rh stored as bf16, 8 slices of 32 elems (64B data + 16B pad = 80B) per batch
    __shared__ __align__(16) unsigned char hS[2 * 640];
    __shared__ __align__(16) unsigned char rhS[2 * 640];
    __shared__ float xs[2][TT];
    __shared__ float hid[2][HH];

    const int t  = threadIdx.x;
    const int s  = t & 7;          // K-slice 0..7
    const int cq = t >> 3;         // column quad 0..63
    const bool p0 = (t & 1), p1 = (t & 2), p2 = (t & 4);
    const int c_own   = t & 3;             // owned column within quad
    const int b_own   = (t >> 2) & 1;      // owned batch
    const int col_own = 4 * cq + c_own;
    const int b0 = blockIdx.x * 2;

    // ---- per-thread weight registers: 3 gates x 4 cols x 4 uint4 = 192 VGPRs ----
    uint4 wz[4][4], wr[4][4], wh[4][4];
#pragma unroll
    for (int l = 0; l < 4; ++l) {
        const int base = (4 * cq + l) * 128 + s * 16;
        const uint4* pz = (const uint4*)(UzT + base);
        const uint4* pr = (const uint4*)(UrT + base);
        const uint4* ph = (const uint4*)(UhT + base);
#pragma unroll
        for (int u = 0; u < 4; ++u) { wz[l][u] = pz[u]; wr[l][u] = pr[u]; wh[l][u] = ph[u]; }
    }

    // scalar params (uniform)
    const float omega = log1pf(__expf(om_raw[0])) + 1e-6f;
    const float aco   = sigmoidf_(al_raw[0]);
    const float bco   = sigmoidf_(be_raw[0]) * (1.0f - aco * 0.99f);
    const float gma   = gam[0];

    // per-lane (owned-column) params, exact fp32
    const float wz_o = Wzw[col_own], bz_o = Wzb[col_own] + Uzb[col_own];
    const float wr_o = Wrw[col_own], br_o = Wrb[col_own] + Urb[col_own];
    const float wh_o = Whw[col_own], bh_o = Whb[col_own] + Uhb[col_own];
    const float wg_o = Wgw[col_own], bg_o = Wgb[col_own];

    // stage x rows; zero h
    xs[t >> 8][t & 255] = x[(b0 + (t >> 8)) * TT + (t & 255)];
    if (t < 320) ((unsigned*)hS)[t] = 0;

    float h_own = 0.f, z_own = 0.f;
    float eps0 = 1e-6f, sig0 = 1e-6f, eps1 = 1e-6f, sig1 = 1e-6f;
    __syncthreads();

    const int sl_off = s * 80;
    const int wr_off = (col_own >> 5) * 40 + (col_own & 31);  // short index within batch plane

    for (int tt = 0; tt < TT; ++tt) {
        const float x0 = xs[0][tt];
        const float x1 = xs[1][tt];
        const float g0 = omega + aco * eps0 + bco * sig0;
        const float g1 = omega + aco * eps1 + bco * sig1;
        eps0 = x0 * x0; sig0 = g0;
        eps1 = x1 * x1; sig1 = g1;
        const float x_o = p2 ? x1 : x0;
        const float g_o = p2 ? g1 : g0;

        // ---- phase A: z,r partial dots over this thread's K-slice ----
        uint4 ha[4], hb[4];
        {
            const uint4* h0p = (const uint4*)(hS + sl_off);
            const uint4* h1p = (const uint4*)(hS + 640 + sl_off);
#pragma unroll
            for (int u = 0; u < 4; ++u) { ha[u] = h0p[u]; hb[u] = h1p[u]; }
        }
        float az[4][2], ar[4][2];
#pragma unroll
        for (int l = 0; l < 4; ++l) { az[l][0] = 0.f; az[l][1] = 0.f; ar[l][0] = 0.f; ar[l][1] = 0.f; }
#pragma unroll
        for (int l = 0; l < 4; ++l) {
#pragma unroll
            for (int u = 0; u < 4; ++u) {
                uint4 a = wz[l][u], b = wr[l][u];
                DOT2(az[l][0], a.x, ha[u].x); DOT2(az[l][0], a.y, ha[u].y);
                DOT2(az[l][0], a.z, ha[u].z); DOT2(az[l][0], a.w, ha[u].w);
                DOT2(az[l][1], a.x, hb[u].x); DOT2(az[l][1], a.y, hb[u].y);
                DOT2(az[l][1], a.z, hb[u].z); DOT2(az[l][1], a.w, hb[u].w);
                DOT2(ar[l][0], b.x, ha[u].x); DOT2(ar[l][0], b.y, ha[u].y);
                DOT2(ar[l][0], b.z, ha[u].z); DOT2(ar[l][0], b.w, ha[u].w);
                DOT2(ar[l][1], b.x, hb[u].x); DOT2(ar[l][1], b.y, hb[u].y);
                DOT2(ar[l][1], b.z, hb[u].z); DOT2(ar[l][1], b.w, hb[u].w);
            }
        }
        // ---- DPP reduce-scatter: lane ends with full sum for (c_own, b_own) ----
        float z1a[2][2], r1a[2][2];
        RCOMB(z1a[0][0], az[0][0], az[1][0], p0, 0xB1);
        RCOMB(z1a[0][1], az[0][1], az[1][1], p0, 0xB1);
        RCOMB(z1a[1][0], az[2][0], az[3][0], p0, 0xB1);
        RCOMB(z1a[1][1], az[2][1], az[3][1], p0, 0xB1);
        RCOMB(r1a[0][0], ar[0][0], ar[1][0], p0, 0xB1);
        RCOMB(r1a[0][1], ar[0][1], ar[1][1], p0, 0xB1);
        RCOMB(r1a[1][0], ar[2][0], ar[3][0], p0, 0xB1);
        RCOMB(r1a[1][1], ar[2][1], ar[3][1], p0, 0xB1);
        float z2a[2], r2a[2];
        RCOMB(z2a[0], z1a[0][0], z1a[1][0], p1, 0x4E);
        RCOMB(z2a[1], z1a[0][1], z1a[1][1], p1, 0x4E);
        RCOMB(r2a[0], r1a[0][0], r1a[1][0], p1, 0x4E);
        RCOMB(r2a[1], r1a[0][1], r1a[1][1], p1, 0x4E);
        float accZ, accR;
        RCOMB4(accZ, z2a[0], z2a[1], p2);
        RCOMB4(accR, r2a[0], r2a[1], p2);

        z_own = sigmoidf_(accZ + x_o * wz_o + bz_o);
        const float r = sigmoidf_(accR + x_o * wr_o + br_o);
        ((unsigned short*)(rhS + b_own * 640))[wr_off] = (unsigned short)f2bf_rne(r * h_own);
        __syncthreads();

        // ---- phase B: candidate gate ----
        uint4 pa[4], pb[4];
        {
            const uint4* r0p = (const uint4*)(rhS + sl_off);
            const uint4* r1p = (const uint4*)(rhS + 640 + sl_off);
#pragma unroll
            for (int u = 0; u < 4; ++u) { pa[u] = r0p[u]; pb[u] = r1p[u]; }
        }
        float ah[4][2];
#pragma unroll
        for (int l = 0; l < 4; ++l) { ah[l][0] = 0.f; ah[l][1] = 0.f; }
#pragma unroll
        for (int l = 0; l < 4; ++l) {
#pragma unroll
            for (int u = 0; u < 4; ++u) {
                uint4 a = wh[l][u];
                DOT2(ah[l][0], a.x, pa[u].x); DOT2(ah[l][0], a.y, pa[u].y);
                DOT2(ah[l][0], a.z, pa[u].z); DOT2(ah[l][0], a.w, pa[u].w);
                DOT2(ah[l][1], a.x, pb[u].x); DOT2(ah[l][1], a.y, pb[u].y);
                DOT2(ah[l][1], a.z, pb[u].z); DOT2(ah[l][1], a.w, pb[u].w);
            }
        }
        float h1a[2][2];
        RCOMB(h1a[0][0], ah[0][0], ah[1][0], p0, 0xB1);
        RCOMB(h1a[0][1], ah[0][1], ah[1][1], p0, 0xB1);
        RCOMB(h1a[1][0], ah[2][0], ah[3][0], p0, 0xB1);
        RCOMB(h1a[1][1], ah[2][1], ah[3][1], p0, 0xB1);
        float h2a[2];
        RCOMB(h2a[0], h1a[0][0], h1a[1][0], p1, 0x4E);
        RCOMB(h2a[1], h1a[0][1], h1a[1][1], p1, 0x4E);
        float accH;
        RCOMB4(accH, h2a[0], h2a[1], p2);

        const float htld = tanhf_(accH + x_o * wh_o + bh_o);
        const float hh   = (1.f - z_own) * htld + z_own * h_own;
        const float hn   = tanhf_(hh + gma * (g_o * wg_o + bg_o));
        h_own = hn;
        ((unsigned short*)(hS + b_own * 640))[wr_off] = (unsigned short)f2bf_rne(hn);
        __syncthreads();
    }

    // ---- stash exact fp32 h (reuse xs) ----
    xs[b_own][col_own] = h_own;
    __syncthreads();

    // ---- head: hid = relu(h @ fc1 + b1) ----
    {
        const int b = t >> 8, j = t & 255;
        float acc = 0.f;
#pragma unroll 4
        for (int k = 0; k < HH; ++k) acc += xs[b][k] * fc1w[k * HH + j];
        hid[b][j] = fmaxf(acc + fc1b[j], 0.f);
    }
    __syncthreads();

    // ---- head: nn_scale / vol ----
    if (t < 2 * HOR) {
        const int b = t / HOR;
        const int c = t % HOR;
        float acc = fc2b[c];
        for (int k = 0; k < HH; ++k) acc += hid[b][k] * fc2w[k * HOR + c];
        const float sp = log1pf(__expf(acc));
        const float sg = b ? sig1 : sig0;
        const float vb = sqrtf(sg + 1e-8f);
        float vol = vb * (1.0f + sp);
        vol = fminf(fmaxf(vol, 0.01f), 10.0f);
        out[(b0 + b) * HOR + c] = vol;
    }
    if (t == 0) out[BATCH * HOR + b0]     = sig0;
    if (t == 1) out[BATCH * HOR + b0 + 1] = sig1;
}

extern "C" void kernel_launch(void* const* d_in, const int* in_sizes, int n_in,
                              void* d_out, int out_size, void* d_ws, size_t ws_size,
                              hipStream_t stream) {
    const float* x    = (const float*)d_in[0];
    const float* Wzw  = (const float*)d_in[1];
    const float* Wzb  = (const float*)d_in[2];
    const float* Uzw  = (const float*)d_in[3];
    const float* Uzb  = (const float*)d_in[4];
    const float* Wrw  = (const float*)d_in[5];
    const float* Wrb  = (const float*)d_in[6];
    const float* Urw  = (const float*)d_in[7];
    const float* Urb  = (const float*)d_in[8];
    const float* Whw  = (const float*)d_in[9];
    const float* Whb  = (const float*)d_in[10];
    const float* Uhw  = (const float*)d_in[11];
    const float* Uhb  = (const float*)d_in[12];
    const float* Wgw  = (const float*)d_in[13];
    const float* Wgb  = (const float*)d_in[14];
    const float* om   = (const float*)d_in[15];
    const float* al   = (const float*)d_in[16];
    const float* be   = (const float*)d_in[17];
    const float* ga   = (const float*)d_in[18];
    const float* fc1w = (const float*)d_in[19];
    const float* fc1b = (const float*)d_in[20];
    const float* fc2w = (const float*)d_in[21];
    const float* fc2b = (const float*)d_in[22];

    unsigned* UzT = (unsigned*)d_ws;       // 32768 uints each
    unsigned* UrT = UzT + 32768;
    unsigned* UhT = UrT + 32768;

    prep_kernel<<<384, 256, 0, stream>>>(Uzw, Urw, Uhw, UzT, UrT, UhT);
    gru_kernel<<<256, 512, 0, stream>>>(x, Wzw, Wzb, Uzb, Wrw, Wrb, Urb, Whw, Whb, Uhb,
                                        Wgw, Wgb, om, al, be, ga, fc1w, fc1b, fc2w, fc2b,
                                        UzT, UrT, UhT, (float*)d_out);
}

// Round 4
// 781.347 us; speedup vs baseline: 3.8192x; 1.0206x over previous
//
#include <hip/hip_runtime.h>

#define BATCH 512
#define TT 256
#define HH 256
#define HOR 22

__device__ __forceinline__ float bf16lo(unsigned u) { return __uint_as_float(u << 16); }
__device__ __forceinline__ float bf16hi(unsigned u) { return __uint_as_float(u & 0xFFFF0000u); }
__device__ __forceinline__ float rcp_(float x) { return __builtin_amdgcn_rcpf(x); }
__device__ __forceinline__ float sigmoidf_(float x) { return rcp_(1.0f + __expf(-x)); }
__device__ __forceinline__ float tanhf_(float x) {
    float e = __expf(-2.0f * fabsf(x));
    float t = (1.0f - e) * rcp_(1.0f + e);
    return copysignf(t, x);
}
__device__ __forceinline__ unsigned f2bf_rne(float f) {
    unsigned u = __float_as_uint(f);
    unsigned lsb = (u >> 16) & 1u;
    return (u + 0x7FFFu + lsb) >> 16;
}

// v_dot2_f32_bf16: acc += a.lo*b.lo + a.hi*b.hi (packed bf16 pairs)
#define DOT2(acc, a, b) asm("v_dot2_f32_bf16 %0, %1, %2, %0" : "+v"(acc) : "v"(a), "v"(b))

// zero-instruction compiler barrier: pins a value into a register and kills
// rematerialization of its defining load (round-3 failure mode: weights were
// re-loaded from global every step -> L2-BW-bound at ~32 TB/s)
#define PIN(v) asm volatile("" : "+v"(v))
#define PIN4(q) { PIN((q).x); PIN((q).y); PIN((q).z); PIN((q).w); }

// DPP cross-lane (VALU pipe, no LDS)
#define DPPF(x, ctrl) __int_as_float(__builtin_amdgcn_update_dpp(0, __float_as_int(x), (ctrl), 0xF, 0xF, true))
#define RCOMB(out, a, b, p, ctrl)                          \
    {                                                      \
        float _ta = (a) + DPPF((a), ctrl);                 \
        float _tb = (b) + DPPF((b), ctrl);                 \
        (out) = (p) ? _tb : _ta;                           \
    }
#define RCOMB4(out, a, b, p2v)                                         \
    {                                                                  \
        float _xa = (p2v) ? DPPF((a), 0x114) : DPPF((a), 0x104);       \
        float _xb = (p2v) ? DPPF((b), 0x114) : DPPF((b), 0x104);       \
        float _ta = (a) + _xa;                                         \
        float _tb = (b) + _xb;                                         \
        (out) = (p2v) ? _tb : _ta;                                     \
    }

// ---------------- prep: transpose U matrices to packed-bf16 rows UT[col][kpair] ----------------
__global__ __launch_bounds__(256) void prep_kernel(const float* __restrict__ Uz,
                                                   const float* __restrict__ Ur,
                                                   const float* __restrict__ Uh,
                                                   unsigned* __restrict__ UzT,
                                                   unsigned* __restrict__ UrT,
                                                   unsigned* __restrict__ UhT) {
    int tid = blockIdx.x * 256 + threadIdx.x;   // 0 .. 98303
    int m  = tid >> 15;
    int r  = tid & 32767;
    int j  = r & 255;
    int kp = r >> 8;
    const float* src = (m == 0) ? Uz : (m == 1) ? Ur : Uh;
    unsigned*    dst = (m == 0) ? UzT : (m == 1) ? UrT : UhT;
    float a0 = src[(2 * kp)     * HH + j];
    float a1 = src[(2 * kp + 1) * HH + j];
    dst[j * (HH / 2) + kp] = f2bf_rne(a0) | (f2bf_rne(a1) << 16);
}

// ---------------- persistent GRU: 1 WG = 2 batch rows, 512 thr = 64 col-quads x 8 K-slices ----
__global__ __launch_bounds__(512, 2) void gru_kernel(
    const float* __restrict__ x,
    const float* __restrict__ Wzw, const float* __restrict__ Wzb, const float* __restrict__ Uzb,
    const float* __restrict__ Wrw, const float* __restrict__ Wrb, const float* __restrict__ Urb,
    const float* __restrict__ Whw, const float* __restrict__ Whb, const float* __restrict__ Uhb,
    const float* __restrict__ Wgw, const float* __restrict__ Wgb,
    const float* __restrict__ om_raw, const float* __restrict__ al_raw,
    const float* __restrict__ be_raw, const float* __restrict__ gam,
    const float* __restrict__ fc1w, const float* __restrict__ fc1b,
    const float* __restrict__ fc2w, const float* __restrict__ fc2b,
    const unsigned* __restrict__ UzT, const unsigned* __restrict__ UrT,
    const unsigned* __restrict__ UhT,
    float* __restrict__ out) {
    // h / rh stored as bf16, 8 slices of 32 elems (64B data + 16B pad = 80B) per batch
    __shared__ __align__(16) unsigned char hS[2 * 640];
    __shared__ __align__(16) unsigned char rhS[2 * 640];
    __shared__ float xs[2][TT];
    __shared__ float hid[2][HH];

    const int t  = threadIdx.x;
    const int s  = t & 7;          // K-slice 0..7
    const int cq = t >> 3;         // column quad 0..63
    const bool p0 = (t & 1), p1 = (t & 2), p2 = (t & 4);
    const int c_own   = t & 3;             // owned column within quad
    const int b_own   = (t >> 2) & 1;      // owned batch
    const int col_own = 4 * cq + c_own;
    const int b0 = blockIdx.x * 2;

    // ---- per-thread weight registers: 3 gates x 4 cols x 4 uint4 = 192 VGPRs ----
    uint4 wz[4][4], wr[4][4], wh[4][4];
#pragma unroll
    for (int l = 0; l < 4; ++l) {
        const int base = (4 * cq + l) * 128 + s * 16;
        const uint4* pz = (const uint4*)(UzT + base);
        const uint4* pr = (const uint4*)(UrT + base);
        const uint4* ph = (const uint4*)(UhT + base);
#pragma unroll
        for (int u = 0; u < 4; ++u) { wz[l][u] = pz[u]; wr[l][u] = pr[u]; wh[l][u] = ph[u]; }
    }
#pragma unroll
    for (int l = 0; l < 4; ++l) {
#pragma unroll
        for (int u = 0; u < 4; ++u) { PIN4(wz[l][u]); PIN4(wr[l][u]); PIN4(wh[l][u]); }
    }

    // scalar params (uniform)
    const float omega = log1pf(__expf(om_raw[0])) + 1e-6f;
    const float aco   = sigmoidf_(al_raw[0]);
    const float bco   = sigmoidf_(be_raw[0]) * (1.0f - aco * 0.99f);
    const float gma   = gam[0];

    // per-lane (owned-column) params, exact fp32
    const float wz_o = Wzw[col_own], bz_o = Wzb[col_own] + Uzb[col_own];
    const float wr_o = Wrw[col_own], br_o = Wrb[col_own] + Urb[col_own];
    const float wh_o = Whw[col_own], bh_o = Whb[col_own] + Uhb[col_own];
    const float wg_o = Wgw[col_own], bg_o = Wgb[col_own];

    // stage x rows; zero h
    xs[t >> 8][t & 255] = x[(b0 + (t >> 8)) * TT + (t & 255)];
    if (t < 320) ((unsigned*)hS)[t] = 0;

    float h_own = 0.f, z_own = 0.f;
    float eps0 = 1e-6f, sig0 = 1e-6f, eps1 = 1e-6f, sig1 = 1e-6f;
    __syncthreads();

    const int sl_off = s * 80;
    const int wr_off = (col_own >> 5) * 40 + (col_own & 31);  // short index within batch plane

    for (int tt = 0; tt < TT; ++tt) {
        const float x0 = xs[0][tt];
        const float x1 = xs[1][tt];
        const float g0 = omega + aco * eps0 + bco * sig0;
        const float g1 = omega + aco * eps1 + bco * sig1;
        eps0 = x0 * x0; sig0 = g0;
        eps1 = x1 * x1; sig1 = g1;
        const float x_o = p2 ? x1 : x0;
        const float g_o = p2 ? g1 : g0;

        // ---- phase A: z,r partial dots over this thread's K-slice ----
        uint4 ha[4], hb[4];
        {
            const uint4* h0p = (const uint4*)(hS + sl_off);
            const uint4* h1p = (const uint4*)(hS + 640 + sl_off);
#pragma unroll
            for (int u = 0; u < 4; ++u) { ha[u] = h0p[u]; hb[u] = h1p[u]; }
        }
        float az[4][2], ar[4][2];
#pragma unroll
        for (int l = 0; l < 4; ++l) { az[l][0] = 0.f; az[l][1] = 0.f; ar[l][0] = 0.f; ar[l][1] = 0.f; }
#pragma unroll
        for (int l = 0; l < 4; ++l) {
#pragma unroll
            for (int u = 0; u < 4; ++u) {
                uint4 a = wz[l][u], b = wr[l][u];
                DOT2(az[l][0], a.x, ha[u].x); DOT2(az[l][0], a.y, ha[u].y);
                DOT2(az[l][0], a.z, ha[u].z); DOT2(az[l][0], a.w, ha[u].w);
                DOT2(az[l][1], a.x, hb[u].x); DOT2(az[l][1], a.y, hb[u].y);
                DOT2(az[l][1], a.z, hb[u].z); DOT2(az[l][1], a.w, hb[u].w);
                DOT2(ar[l][0], b.x, ha[u].x); DOT2(ar[l][0], b.y, ha[u].y);
                DOT2(ar[l][0], b.z, ha[u].z); DOT2(ar[l][0], b.w, ha[u].w);
                DOT2(ar[l][1], b.x, hb[u].x); DOT2(ar[l][1], b.y, hb[u].y);
                DOT2(ar[l][1], b.z, hb[u].z); DOT2(ar[l][1], b.w, hb[u].w);
            }
        }
        // ---- DPP reduce-scatter: lane ends with full sum for (c_own, b_own) ----
        float z1a[2][2], r1a[2][2];
        RCOMB(z1a[0][0], az[0][0], az[1][0], p0, 0xB1);
        RCOMB(z1a[0][1], az[0][1], az[1][1], p0, 0xB1);
        RCOMB(z1a[1][0], az[2][0], az[3][0], p0, 0xB1);
        RCOMB(z1a[1][1], az[2][1], az[3][1], p0, 0xB1);
        RCOMB(r1a[0][0], ar[0][0], ar[1][0], p0, 0xB1);
        RCOMB(r1a[0][1], ar[0][1], ar[1][1], p0, 0xB1);
        RCOMB(r1a[1][0], ar[2][0], ar[3][0], p0, 0xB1);
        RCOMB(r1a[1][1], ar[2][1], ar[3][1], p0, 0xB1);
        float z2a[2], r2a[2];
        RCOMB(z2a[0], z1a[0][0], z1a[1][0], p1, 0x4E);
        RCOMB(z2a[1], z1a[0][1], z1a[1][1], p1, 0x4E);
        RCOMB(r2a[0], r1a[0][0], r1a[1][0], p1, 0x4E);
        RCOMB(r2a[1], r1a[0][1], r1a[1][1], p1, 0x4E);
        float accZ, accR;
        RCOMB4(accZ, z2a[0], z2a[1], p2);
        RCOMB4(accR, r2a[0], r2a[1], p2);

        z_own = sigmoidf_(accZ + x_o * wz_o + bz_o);
        const float r = sigmoidf_(accR + x_o * wr_o + br_o);
        ((unsigned short*)(rhS + b_own * 640))[wr_off] = (unsigned short)f2bf_rne(r * h_own);
        __syncthreads();

        // ---- phase B: candidate gate ----
        uint4 pa[4], pb[4];
        {
            const uint4* r0p = (const uint4*)(rhS + sl_off);
            const uint4* r1p = (const uint4*)(rhS + 640 + sl_off);
#pragma unroll
            for (int u = 0; u < 4; ++u) { pa[u] = r0p[u]; pb[u] = r1p[u]; }
        }
        float ah[4][2];
#pragma unroll
        for (int l = 0; l < 4; ++l) { ah[l][0] = 0.f; ah[l][1] = 0.f; }
#pragma unroll
        for (int l = 0; l < 4; ++l) {
#pragma unroll
            for (int u = 0; u < 4; ++u) {
                uint4 a = wh[l][u];
                DOT2(ah[l][0], a.x, pa[u].x); DOT2(ah[l][0], a.y, pa[u].y);
                DOT2(ah[l][0], a.z, pa[u].z); DOT2(ah[l][0], a.w, pa[u].w);
                DOT2(ah[l][1], a.x, pb[u].x); DOT2(ah[l][1], a.y, pb[u].y);
                DOT2(ah[l][1], a.z, pb[u].z); DOT2(ah[l][1], a.w, pb[u].w);
            }
        }
        float h1a[2][2];
        RCOMB(h1a[0][0], ah[0][0], ah[1][0], p0, 0xB1);
        RCOMB(h1a[0][1], ah[0][1], ah[1][1], p0, 0xB1);
        RCOMB(h1a[1][0], ah[2][0], ah[3][0], p0, 0xB1);
        RCOMB(h1a[1][1], ah[2][1], ah[3][1], p0, 0xB1);
        float h2a[2];
        RCOMB(h2a[0], h1a[0][0], h1a[1][0], p1, 0x4E);
        RCOMB(h2a[1], h1a[0][1], h1a[1][1], p1, 0x4E);
        float accH;
        RCOMB4(accH, h2a[0], h2a[1], p2);

        const float htld = tanhf_(accH + x_o * wh_o + bh_o);
        const float hh   = (1.f - z_own) * htld + z_own * h_own;
        const float hn   = tanhf_(hh + gma * (g_o * wg_o + bg_o));
        h_own = hn;
        ((unsigned short*)(hS + b_own * 640))[wr_off] = (unsigned short)f2bf_rne(hn);
        __syncthreads();
    }

    // ---- stash exact fp32 h (reuse xs) ----
    xs[b_own][col_own] = h_own;
    __syncthreads();

    // ---- head: hid = relu(h @ fc1 + b1) ----
    {
        const int b = t >> 8, j = t & 255;
        float acc = 0.f;
#pragma unroll 4
        for (int k = 0; k < HH; ++k) acc += xs[b][k] * fc1w[k * HH + j];
        hid[b][j] = fmaxf(acc + fc1b[j], 0.f);
    }
    __syncthreads();

    // ---- head: nn_scale / vol ----
    if (t < 2 * HOR) {
        const int b = t / HOR;
        const int c = t % HOR;
        float acc = fc2b[c];
        for (int k = 0; k < HH; ++k) acc += hid[b][k] * fc2w[k * HOR + c];
        const float sp = log1pf(__expf(acc));
        const float sg = b ? sig1 : sig0;
        const float vb = sqrtf(sg + 1e-8f);
        float vol = vb * (1.0f + sp);
        vol = fminf(fmaxf(vol, 0.01f), 10.0f);
        out[(b0 + b) * HOR + c] = vol;
    }
    if (t == 0) out[BATCH * HOR + b0]     = sig0;
    if (t == 1) out[BATCH * HOR + b0 + 1] = sig1;
}

extern "C" void kernel_launch(void* const* d_in, const int* in_sizes, int n_in,
                              void* d_out, int out_size, void* d_ws, size_t ws_size,
                              hipStream_t stream) {
    const float* x    = (const float*)d_in[0];
    const float* Wzw  = (const float*)d_in[1];
    const float* Wzb  = (const float*)d_in[2];
    const float* Uzw  = (const float*)d_in[3];
    const float* Uzb  = (const float*)d_in[4];
    const float* Wrw  = (const float*)d_in[5];
    const float* Wrb  = (const float*)d_in[6];
    const float* Urw  = (const float*)d_in[7];
    const float* Urb  = (const float*)d_in[8];
    const float* Whw  = (const float*)d_in[9];
    const float* Whb  = (const float*)d_in[10];
    const float* Uhw  = (const float*)d_in[11];
    const float* Uhb  = (const float*)d_in[12];
    const float* Wgw  = (const float*)d_in[13];
    const float* Wgb  = (const float*)d_in[14];
    const float* om   = (const float*)d_in[15];
    const float* al   = (const float*)d_in[16];
    const float* be   = (const float*)d_in[17];
    const float* ga   = (const float*)d_in[18];
    const float* fc1w = (const float*)d_in[19];
    const float* fc1b = (const float*)d_in[20];
    const float* fc2w = (const float*)d_in[21];
    const float* fc2b = (const float*)d_in[22];

    unsigned* UzT = (unsigned*)d_ws;       // 32768 uints each
    unsigned* UrT = UzT + 32768;
    unsigned* UhT = UrT + 32768;

    prep_kernel<<<384, 256, 0, stream>>>(Uzw, Urw, Uhw, UzT, UrT, UhT);
    gru_kernel<<<256, 512, 0, stream>>>(x, Wzw, Wzb, Uzb, Wrw, Wrb, Urb, Whw, Whb, Uhb,
                                        Wgw, Wgb, om, al, be, ga, fc1w, fc1b, fc2w, fc2b,
                                        UzT, UrT, UhT, (float*)d_out);
}

// Round 5
// 780.279 us; speedup vs baseline: 3.8244x; 1.0014x over previous
//
#include <hip/hip_runtime.h>

#define BATCH 512
#define TT 256
#define HH 256
#define HOR 22

__device__ __forceinline__ float bf16lo(unsigned u) { return __uint_as_float(u << 16); }
__device__ __forceinline__ float bf16hi(unsigned u) { return __uint_as_float(u & 0xFFFF0000u); }
__device__ __forceinline__ float rcp_(float x) { return __builtin_amdgcn_rcpf(x); }
__device__ __forceinline__ float sigmoidf_(float x) { return rcp_(1.0f + __expf(-x)); }
__device__ __forceinline__ float tanhf_(float x) {
    float e = __expf(-2.0f * fabsf(x));
    float t = (1.0f - e) * rcp_(1.0f + e);
    return copysignf(t, x);
}
__device__ __forceinline__ unsigned f2bf_rne(float f) {
    unsigned u = __float_as_uint(f);
    unsigned lsb = (u >> 16) & 1u;
    return (u + 0x7FFFu + lsb) >> 16;
}

// v_dot2_f32_bf16: acc += a.lo*b.lo + a.hi*b.hi (packed bf16 pairs)
#define DOT2(acc, a, b) asm("v_dot2_f32_bf16 %0, %1, %2, %0" : "+v"(acc) : "v"(a), "v"(b))

// zero-instruction compiler barrier: pins a value into a register and kills
// rematerialization of its defining load. Only effective when the register
// budget allows residency -> see amdgpu_waves_per_eu(2,2) below.
#define PIN(v) asm volatile("" : "+v"(v))
#define PIN4(q) { PIN((q).x); PIN((q).y); PIN((q).z); PIN((q).w); }

// DPP cross-lane (VALU pipe, no LDS)
#define DPPF(x, ctrl) __int_as_float(__builtin_amdgcn_update_dpp(0, __float_as_int(x), (ctrl), 0xF, 0xF, true))
#define RCOMB(out, a, b, p, ctrl)                          \
    {                                                      \
        float _ta = (a) + DPPF((a), ctrl);                 \
        float _tb = (b) + DPPF((b), ctrl);                 \
        (out) = (p) ? _tb : _ta;                           \
    }
#define RCOMB4(out, a, b, p2v)                                         \
    {                                                                  \
        float _xa = (p2v) ? DPPF((a), 0x114) : DPPF((a), 0x104);       \
        float _xb = (p2v) ? DPPF((b), 0x114) : DPPF((b), 0x104);       \
        float _ta = (a) + _xa;                                         \
        float _tb = (b) + _xb;                                         \
        (out) = (p2v) ? _tb : _ta;                                     \
    }

// ---------------- prep: transpose U matrices to packed-bf16 rows UT[col][kpair] ----------------
__global__ __launch_bounds__(256) void prep_kernel(const float* __restrict__ Uz,
                                                   const float* __restrict__ Ur,
                                                   const float* __restrict__ Uh,
                                                   unsigned* __restrict__ UzT,
                                                   unsigned* __restrict__ UrT,
                                                   unsigned* __restrict__ UhT) {
    int tid = blockIdx.x * 256 + threadIdx.x;   // 0 .. 98303
    int m  = tid >> 15;
    int r  = tid & 32767;
    int j  = r & 255;
    int kp = r >> 8;
    const float* src = (m == 0) ? Uz : (m == 1) ? Ur : Uh;
    unsigned*    dst = (m == 0) ? UzT : (m == 1) ? UrT : UhT;
    float a0 = src[(2 * kp)     * HH + j];
    float a1 = src[(2 * kp + 1) * HH + j];
    dst[j * (HH / 2) + kp] = f2bf_rne(a0) | (f2bf_rne(a1) << 16);
}

// ---------------- persistent GRU: 1 WG = 2 batch rows, 512 thr = 64 col-quads x 8 K-slices ----
// amdgpu_waves_per_eu(2,2): exactly 2 waves/SIMD -> 256-VGPR budget per wave, so the
// 192 weight registers stay resident. (launch_bounds(512,2) was interpreted as
// min-2-blocks/CU -> 128-reg clamp -> weights re-streamed from L2 at ~33 TB/s.)
__global__ __launch_bounds__(512) __attribute__((amdgpu_waves_per_eu(2, 2))) void gru_kernel(
    const float* __restrict__ x,
    const float* __restrict__ Wzw, const float* __restrict__ Wzb, const float* __restrict__ Uzb,
    const float* __restrict__ Wrw, const float* __restrict__ Wrb, const float* __restrict__ Urb,
    const float* __restrict__ Whw, const float* __restrict__ Whb, const float* __restrict__ Uhb,
    const float* __restrict__ Wgw, const float* __restrict__ Wgb,
    const float* __restrict__ om_raw, const float* __restrict__ al_raw,
    const float* __restrict__ be_raw, const float* __restrict__ gam,
    const float* __restrict__ fc1w, const float* __restrict__ fc1b,
    const float* __restrict__ fc2w, const float* __restrict__ fc2b,
    const unsigned* __restrict__ UzT, const unsigned* __restrict__ UrT,
    const unsigned* __restrict__ UhT,
    float* __restrict__ out) {
    // h / rh stored as bf16, 8 slices of 32 elems (64B data + 16B pad = 80B) per batch
    __shared__ __align__(16) unsigned char hS[2 * 640];
    __shared__ __align__(16) unsigned char rhS[2 * 640];
    __shared__ float xs[2][TT];
    __shared__ float hid[2][HH];

    const int t  = threadIdx.x;
    const int s  = t & 7;          // K-slice 0..7
    const int cq = t >> 3;         // column quad 0..63
    const bool p0 = (t & 1), p1 = (t & 2), p2 = (t & 4);
    const int c_own   = t & 3;             // owned column within quad
    const int b_own   = (t >> 2) & 1;      // owned batch
    const int col_own = 4 * cq + c_own;
    const int b0 = blockIdx.x * 2;

    // ---- per-thread weight registers: 3 gates x 4 cols x 4 uint4 = 192 VGPRs ----
    uint4 wz[4][4], wr[4][4], wh[4][4];
#pragma unroll
    for (int l = 0; l < 4; ++l) {
        const int base = (4 * cq + l) * 128 + s * 16;
        const uint4* pz = (const uint4*)(UzT + base);
        const uint4* pr = (const uint4*)(UrT + base);
        const uint4* ph = (const uint4*)(UhT + base);
#pragma unroll
        for (int u = 0; u < 4; ++u) { wz[l][u] = pz[u]; wr[l][u] = pr[u]; wh[l][u] = ph[u]; }
    }
#pragma unroll
    for (int l = 0; l < 4; ++l) {
#pragma unroll
        for (int u = 0; u < 4; ++u) { PIN4(wz[l][u]); PIN4(wr[l][u]); PIN4(wh[l][u]); }
    }

    // scalar params (uniform)
    const float omega = log1pf(__expf(om_raw[0])) + 1e-6f;
    const float aco   = sigmoidf_(al_raw[0]);
    const float bco   = sigmoidf_(be_raw[0]) * (1.0f - aco * 0.99f);
    const float gma   = gam[0];

    // per-lane (owned-column) params, exact fp32
    const float wz_o = Wzw[col_own], bz_o = Wzb[col_own] + Uzb[col_own];
    const float wr_o = Wrw[col_own], br_o = Wrb[col_own] + Urb[col_own];
    const float wh_o = Whw[col_own], bh_o = Whb[col_own] + Uhb[col_own];
    const float wg_o = Wgw[col_own], bg_o = Wgb[col_own];

    // stage x rows; zero h
    xs[t >> 8][t & 255] = x[(b0 + (t >> 8)) * TT + (t & 255)];
    if (t < 320) ((unsigned*)hS)[t] = 0;

    float h_own = 0.f, z_own = 0.f;
    float eps0 = 1e-6f, sig0 = 1e-6f, eps1 = 1e-6f, sig1 = 1e-6f;
    __syncthreads();

    const int sl_off = s * 80;
    const int wr_off = (col_own >> 5) * 40 + (col_own & 31);  // short index within batch plane

    for (int tt = 0; tt < TT; ++tt) {
        const float x0 = xs[0][tt];
        const float x1 = xs[1][tt];
        const float g0 = omega + aco * eps0 + bco * sig0;
        const float g1 = omega + aco * eps1 + bco * sig1;
        eps0 = x0 * x0; sig0 = g0;
        eps1 = x1 * x1; sig1 = g1;
        const float x_o = p2 ? x1 : x0;
        const float g_o = p2 ? g1 : g0;

        // ---- phase A: z,r partial dots over this thread's K-slice ----
        uint4 ha[4], hb[4];
        {
            const uint4* h0p = (const uint4*)(hS + sl_off);
            const uint4* h1p = (const uint4*)(hS + 640 + sl_off);
#pragma unroll
            for (int u = 0; u < 4; ++u) { ha[u] = h0p[u]; hb[u] = h1p[u]; }
        }
        float az[4][2], ar[4][2];
#pragma unroll
        for (int l = 0; l < 4; ++l) { az[l][0] = 0.f; az[l][1] = 0.f; ar[l][0] = 0.f; ar[l][1] = 0.f; }
#pragma unroll
        for (int l = 0; l < 4; ++l) {
#pragma unroll
            for (int u = 0; u < 4; ++u) {
                uint4 a = wz[l][u], b = wr[l][u];
                DOT2(az[l][0], a.x, ha[u].x); DOT2(az[l][0], a.y, ha[u].y);
                DOT2(az[l][0], a.z, ha[u].z); DOT2(az[l][0], a.w, ha[u].w);
                DOT2(az[l][1], a.x, hb[u].x); DOT2(az[l][1], a.y, hb[u].y);
                DOT2(az[l][1], a.z, hb[u].z); DOT2(az[l][1], a.w, hb[u].w);
                DOT2(ar[l][0], b.x, ha[u].x); DOT2(ar[l][0], b.y, ha[u].y);
                DOT2(ar[l][0], b.z, ha[u].z); DOT2(ar[l][0], b.w, ha[u].w);
                DOT2(ar[l][1], b.x, hb[u].x); DOT2(ar[l][1], b.y, hb[u].y);
                DOT2(ar[l][1], b.z, hb[u].z); DOT2(ar[l][1], b.w, hb[u].w);
            }
        }
        // ---- DPP reduce-scatter: lane ends with full sum for (c_own, b_own) ----
        float z1a[2][2], r1a[2][2];
        RCOMB(z1a[0][0], az[0][0], az[1][0], p0, 0xB1);
        RCOMB(z1a[0][1], az[0][1], az[1][1], p0, 0xB1);
        RCOMB(z1a[1][0], az[2][0], az[3][0], p0, 0xB1);
        RCOMB(z1a[1][1], az[2][1], az[3][1], p0, 0xB1);
        RCOMB(r1a[0][0], ar[0][0], ar[1][0], p0, 0xB1);
        RCOMB(r1a[0][1], ar[0][1], ar[1][1], p0, 0xB1);
        RCOMB(r1a[1][0], ar[2][0], ar[3][0], p0, 0xB1);
        RCOMB(r1a[1][1], ar[2][1], ar[3][1], p0, 0xB1);
        float z2a[2], r2a[2];
        RCOMB(z2a[0], z1a[0][0], z1a[1][0], p1, 0x4E);
        RCOMB(z2a[1], z1a[0][1], z1a[1][1], p1, 0x4E);
        RCOMB(r2a[0], r1a[0][0], r1a[1][0], p1, 0x4E);
        RCOMB(r2a[1], r1a[0][1], r1a[1][1], p1, 0x4E);
        float accZ, accR;
        RCOMB4(accZ, z2a[0], z2a[1], p2);
        RCOMB4(accR, r2a[0], r2a[1], p2);

        z_own = sigmoidf_(accZ + x_o * wz_o + bz_o);
        const float r = sigmoidf_(accR + x_o * wr_o + br_o);
        ((unsigned short*)(rhS + b_own * 640))[wr_off] = (unsigned short)f2bf_rne(r * h_own);
        __syncthreads();

        // ---- phase B: candidate gate ----
        uint4 pa[4], pb[4];
        {
            const uint4* r0p = (const uint4*)(rhS + sl_off);
            const uint4* r1p = (const uint4*)(rhS + 640 + sl_off);
#pragma unroll
            for (int u = 0; u < 4; ++u) { pa[u] = r0p[u]; pb[u] = r1p[u]; }
        }
        float ah[4][2];
#pragma unroll
        for (int l = 0; l < 4; ++l) { ah[l][0] = 0.f; ah[l][1] = 0.f; }
#pragma unroll
        for (int l = 0; l < 4; ++l) {
#pragma unroll
            for (int u = 0; u < 4; ++u) {
                uint4 a = wh[l][u];
                DOT2(ah[l][0], a.x, pa[u].x); DOT2(ah[l][0], a.y, pa[u].y);
                DOT2(ah[l][0], a.z, pa[u].z); DOT2(ah[l][0], a.w, pa[u].w);
                DOT2(ah[l][1], a.x, pb[u].x); DOT2(ah[l][1], a.y, pb[u].y);
                DOT2(ah[l][1], a.z, pb[u].z); DOT2(ah[l][1], a.w, pb[u].w);
            }
        }
        float h1a[2][2];
        RCOMB(h1a[0][0], ah[0][0], ah[1][0], p0, 0xB1);
        RCOMB(h1a[0][1], ah[0][1], ah[1][1], p0, 0xB1);
        RCOMB(h1a[1][0], ah[2][0], ah[3][0], p0, 0xB1);
        RCOMB(h1a[1][1], ah[2][1], ah[3][1], p0, 0xB1);
        float h2a[2];
        RCOMB(h2a[0], h1a[0][0], h1a[1][0], p1, 0x4E);
        RCOMB(h2a[1], h1a[0][1], h1a[1][1], p1, 0x4E);
        float accH;
        RCOMB4(accH, h2a[0], h2a[1], p2);

        const float htld = tanhf_(accH + x_o * wh_o + bh_o);
        const float hh   = (1.f - z_own) * htld + z_own * h_own;
        const float hn   = tanhf_(hh + gma * (g_o * wg_o + bg_o));
        h_own = hn;
        ((unsigned short*)(hS + b_own * 640))[wr_off] = (unsigned short)f2bf_rne(hn);
        __syncthreads();
    }

    // ---- stash exact fp32 h (reuse xs) ----
    xs[b_own][col_own] = h_own;
    __syncthreads();

    // ---- head: hid = relu(h @ fc1 + b1) ----
    {
        const int b = t >> 8, j = t & 255;
        float acc = 0.f;
#pragma unroll 4
        for (int k = 0; k < HH; ++k) acc += xs[b][k] * fc1w[k * HH + j];
        hid[b][j] = fmaxf(acc + fc1b[j], 0.f);
    }
    __syncthreads();

    // ---- head: nn_scale / vol ----
    if (t < 2 * HOR) {
        const int b = t / HOR;
        const int c = t % HOR;
        float acc = fc2b[c];
        for (int k = 0; k < HH; ++k) acc += hid[b][k] * fc2w[k * HOR + c];
        const float sp = log1pf(__expf(acc));
        const float sg = b ? sig1 : sig0;
        const float vb = sqrtf(sg + 1e-8f);
        float vol = vb * (1.0f + sp);
        vol = fminf(fmaxf(vol, 0.01f), 10.0f);
        out[(b0 + b) * HOR + c] = vol;
    }
    if (t == 0) out[BATCH * HOR + b0]     = sig0;
    if (t == 1) out[BATCH * HOR + b0 + 1] = sig1;
}

extern "C" void kernel_launch(void* const* d_in, const int* in_sizes, int n_in,
                              void* d_out, int out_size, void* d_ws, size_t ws_size,
                              hipStream_t stream) {
    const float* x    = (const float*)d_in[0];
    const float* Wzw  = (const float*)d_in[1];
    const float* Wzb  = (const float*)d_in[2];
    const float* Uzw  = (const float*)d_in[3];
    const float* Uzb  = (const float*)d_in[4];
    const float* Wrw  = (const float*)d_in[5];
    const float* Wrb  = (const float*)d_in[6];
    const float* Urw  = (const float*)d_in[7];
    const float* Urb  = (const float*)d_in[8];
    const float* Whw  = (const float*)d_in[9];
    const float* Whb  = (const float*)d_in[10];
    const float* Uhw  = (const float*)d_in[11];
    const float* Uhb  = (const float*)d_in[12];
    const float* Wgw  = (const float*)d_in[13];
    const float* Wgb  = (const float*)d_in[14];
    const float* om   = (const float*)d_in[15];
    const float* al   = (const float*)d_in[16];
    const float* be   = (const float*)d_in[17];
    const float* ga   = (const float*)d_in[18];
    const float* fc1w = (const float*)d_in[19];
    const float* fc1b = (const float*)d_in[20];
    const float* fc2w = (const float*)d_in[21];
    const float* fc2b = (const float*)d_in[22];

    unsigned* UzT = (unsigned*)d_ws;       // 32768 uints each
    unsigned* UrT = UzT + 32768;
    unsigned* UhT = UrT + 32768;

    prep_kernel<<<384, 256, 0, stream>>>(Uzw, Urw, Uhw, UzT, UrT, UhT);
    gru_kernel<<<256, 512, 0, stream>>>(x, Wzw, Wzb, Uzb, Wrw, Wrb, Urb, Whw, Whb, Uhb,
                                        Wgw, Wgb, om, al, be, ga, fc1w, fc1b, fc2w, fc2b,
                                        UzT, UrT, UhT, (float*)d_out);
}